// Round 3
// baseline (969.338 us; speedup 1.0000x reference)
//
#include <hip/hip_runtime.h>

// MemoryCompressedAttention: B=4, S=4096, D=1024, H=16, DK=64, CR=3, pad=2, Lc=1366.
// Weight-composed bf16 MFMA pipeline:
//   kpj = kpad · (Wk·wc2)^T + (Wk·conv_b + bk)   [conv+proj fused via weight pre-compose]
//   vpj = vpad · (Wv·wc2)^T + (Wv·conv_b + bv)
//   qprj = q · (Wq/8)^T + bq/8
//   attn: MFMA flash, no-max-sub softmax, XOR-swizzled P
//   out  = attn · Wo^T + bo  (fp32)

#define DM   1024
#define NH   16
#define DKH  64
#define BB   4
#define SQ   4096
#define LCC  1366
#define LCP  1408   // padded Lc (22*64)
#define SPAD 4098   // 3*1366

typedef unsigned short u16;
using short8 = __attribute__((ext_vector_type(8))) short;
using f32x4  = __attribute__((ext_vector_type(4))) float;
using us4    = __attribute__((ext_vector_type(4))) unsigned short;
using us8    = __attribute__((ext_vector_type(8))) unsigned short;

__device__ __forceinline__ u16 f2bf(float f) {
    unsigned u = __float_as_uint(f);
    u += 0x7fffu + ((u >> 16) & 1u);      // RTNE
    return (u16)(u >> 16);
}

__device__ __forceinline__ void gl_lds16(const void* g, void* l) {
    __builtin_amdgcn_global_load_lds(
        (__attribute__((address_space(1))) unsigned int*)(uintptr_t)g,
        (__attribute__((address_space(3))) unsigned int*)l,
        16, 0, 0);
}

// ---------------- casts ----------------
__global__ __launch_bounds__(256) void cast4_k(const float* __restrict__ in, u16* __restrict__ out,
                                               int n4, float scale) {
    int i = blockIdx.x * 256 + threadIdx.x;
    if (i >= n4) return;
    float4 v = ((const float4*)in)[i];
    us4 o;
    o[0] = f2bf(v.x * scale); o[1] = f2bf(v.y * scale);
    o[2] = f2bf(v.z * scale); o[3] = f2bf(v.w * scale);
    ((us4*)out)[i] = o;
}

// kpad[b, s, :] = (s<2) ? 0 : key[b, s-2, :]   (bf16)
__global__ __launch_bounds__(256) void cast_pad_k(const float* __restrict__ in, u16* __restrict__ out) {
    int i = blockIdx.x * 256 + threadIdx.x;
    const int n4 = BB * SPAD * DM / 4;
    if (i >= n4) return;
    int e   = i * 4;
    int b   = e / (SPAD * DM);
    int rem = e - b * (SPAD * DM);
    int s   = rem >> 10;
    int d   = rem & (DM - 1);
    us4 o = {0, 0, 0, 0};
    if (s >= 2) {
        float4 v = *(const float4*)(in + (size_t)(b * SQ + (s - 2)) * DM + d);
        o[0] = f2bf(v.x); o[1] = f2bf(v.y); o[2] = f2bf(v.z); o[3] = f2bf(v.w);
    }
    ((us4*)out)[i] = o;
}

// wc2T[(r*1024+i)][c] = conv_w[c][i][r]   (bf16, row stride 1024)
__global__ __launch_bounds__(256) void wc2t_k(const float* __restrict__ cw, u16* __restrict__ wt) {
    __shared__ float t[64][65];
    const int r = blockIdx.z, c0 = blockIdx.y * 64, i0 = blockIdx.x * 64;
    const int tid = threadIdx.x;
    #pragma unroll 4
    for (int it = 0; it < 16; ++it) {
        int c = (tid >> 6) + it * 4, i = tid & 63;
        t[i][c] = cw[(size_t)(c0 + c) * 3072 + (i0 + i) * 3 + r];
    }
    __syncthreads();
    #pragma unroll 4
    for (int it = 0; it < 16; ++it) {
        int i = (tid >> 6) + it * 4, c = tid & 63;
        wt[(size_t)(r * 1024 + i0 + i) * 1024 + c0 + c] = f2bf(t[i][c]);
    }
}

// ob[o] = sum_c W[o][c]*cb[c] + b0[o]   (fp32, one wave per o)
__global__ __launch_bounds__(256) void bias_comp_k(const float* __restrict__ W, const float* __restrict__ cb,
                                                   const float* __restrict__ b0, float* __restrict__ ob) {
    const int wv = threadIdx.x >> 6, lane = threadIdx.x & 63;
    const int o = blockIdx.x * 4 + wv;
    float s = 0.0f;
    for (int c = lane; c < DM; c += 64) s += W[(size_t)o * DM + c] * cb[c];
    #pragma unroll
    for (int off = 32; off; off >>= 1) s += __shfl_down(s, off, 64);
    if (lane == 0) ob[o] = s + b0[o];
}

// vt[(b*16+h)*64 + d][j] = vp[b*1366+j][h*64+d], zero for j>=1366; row stride LCP
__global__ __launch_bounds__(256) void transpose_v_k(const u16* __restrict__ vp, u16* __restrict__ vt) {
    __shared__ u16 t[64 * 64];
    const int tid = threadIdx.x;
    const int j0 = blockIdx.x * 64;
    const int bh = blockIdx.y, b = bh >> 4, h = bh & 15;
    #pragma unroll
    for (int it = 0; it < 2; ++it) {
        int cc = tid + it * 256;
        int j = cc >> 3, d0 = (cc & 7) * 8;
        int jj = j0 + j;
        us8 v = {0, 0, 0, 0, 0, 0, 0, 0};
        if (jj < LCC) v = *(const us8*)(vp + (size_t)(b * LCC + jj) * DM + h * DKH + d0);
        #pragma unroll
        for (int q = 0; q < 8; ++q) t[(d0 + q) * 64 + j] = v[q];
    }
    __syncthreads();
    #pragma unroll
    for (int it = 0; it < 2; ++it) {
        int cc = tid + it * 256;
        int d = cc >> 3, q0 = (cc & 7) * 8;
        *(us8*)(vt + (size_t)(bh * DKH + d) * LCP + j0 + q0) = *(const us8*)(t + d * 64 + q0);
    }
}

// ---------------- MFMA GEMM: C[n,o] = sum_k A[n,k]*Bw[o,k] (+ bias[o]*bscale) ----------------
// blockIdx.z selects (A0,B0,bias0,C0) vs (A1,B1,bias1,C1). C row stride = ldc.
__global__ __launch_bounds__(256, 3) void gemm_mfma_k(
    const u16* __restrict__ A0, const u16* __restrict__ A1,
    const u16* __restrict__ B0, const u16* __restrict__ B1,
    const float* __restrict__ bias0, const float* __restrict__ bias1,
    void* __restrict__ C0, void* __restrict__ C1,
    int N, int K, int ldc, int cf32, float bscale)
{
    __shared__ u16 As[128 * 64];
    __shared__ u16 Bs[128 * 64];
    const u16* A  = blockIdx.z ? A1 : A0;
    const u16* Bw = blockIdx.z ? B1 : B0;
    const float* bias = blockIdx.z ? bias1 : bias0;
    void* C = blockIdx.z ? C1 : C0;

    const int tid = threadIdx.x, wave = tid >> 6, lane = tid & 63;
    const int quad = lane >> 4, l15 = lane & 15;
    const int n0 = blockIdx.y * 128, o0 = blockIdx.x * 128;
    const int wm = (wave >> 1) * 64, wn = (wave & 1) * 64;

    f32x4 acc[4][4];
    #pragma unroll
    for (int a = 0; a < 4; ++a)
        #pragma unroll
        for (int b = 0; b < 4; ++b)
            #pragma unroll
            for (int r = 0; r < 4; ++r) acc[a][b][r] = 0.0f;

    const int srow = (lane >> 3);
    const int sc8  = (lane & 7);

    for (int kt = 0; kt < K; kt += 64) {
        #pragma unroll
        for (int i = 0; i < 4; ++i) {
            int is  = wave * 4 + i;
            int row = is * 8 + srow;
            int c   = sc8 ^ (row & 7);
            int ra  = n0 + row; if (ra > N - 1) ra = N - 1;
            gl_lds16(A  + (size_t)ra * K + kt + c * 8,          As + is * 512 + lane * 8);
            gl_lds16(Bw + (size_t)(o0 + row) * K + kt + c * 8,  Bs + is * 512 + lane * 8);
        }
        __syncthreads();
        #pragma unroll
        for (int ks = 0; ks < 2; ++ks) {
            short8 af[4], bf[4];
            #pragma unroll
            for (int mi = 0; mi < 4; ++mi) {
                int m = wm + mi * 16 + l15;
                int c = (ks * 4 + quad) ^ (m & 7);
                af[mi] = *(const short8*)(As + m * 64 + c * 8);
            }
            #pragma unroll
            for (int nj = 0; nj < 4; ++nj) {
                int n = wn + nj * 16 + l15;
                int c = (ks * 4 + quad) ^ (n & 7);
                bf[nj] = *(const short8*)(Bs + n * 64 + c * 8);
            }
            #pragma unroll
            for (int mi = 0; mi < 4; ++mi)
                #pragma unroll
                for (int nj = 0; nj < 4; ++nj)
                    acc[mi][nj] = __builtin_amdgcn_mfma_f32_16x16x32_bf16(af[mi], bf[nj], acc[mi][nj], 0, 0, 0);
        }
        __syncthreads();
    }
    #pragma unroll
    for (int mi = 0; mi < 4; ++mi) {
        #pragma unroll
        for (int r = 0; r < 4; ++r) {
            int n = n0 + wm + mi * 16 + quad * 4 + r;
            if (n < N) {
                #pragma unroll
                for (int nj = 0; nj < 4; ++nj) {
                    int o = o0 + wn + nj * 16 + l15;
                    float v = acc[mi][nj][r] + (bias ? bias[o] * bscale : 0.0f);
                    if (cf32) ((float*)C)[(size_t)n * ldc + o] = v;
                    else      ((u16*)C)[(size_t)n * ldc + o] = f2bf(v);
                }
            }
        }
    }
}

// ---------------- MFMA flash attention ----------------
// 128 q rows/block; Q frags in registers; Ks/Vts staged via global_load_lds; P XOR-swizzled.
__global__ __launch_bounds__(256, 4) void attn_mfma_k(
    const u16* __restrict__ qp, const u16* __restrict__ kp,
    const u16* __restrict__ vt, u16* __restrict__ xo)
{
    __shared__ u16 Ks[64 * 64];    // swizzled
    __shared__ u16 Vts[64 * 64];   // swizzled, rows = d, cols = kc
    __shared__ u16 Ps[128 * 64];   // XOR-swizzled 16B chunks
    const int tid = threadIdx.x, wave = tid >> 6, lane = tid & 63;
    const int quad = lane >> 4, l15 = lane & 15;
    const int bh = blockIdx.y, b = bh >> 4, h = bh & 15;
    const int s0 = blockIdx.x * 128;
    const int wm = wave * 32;
    const int srow = (lane >> 3), sc8 = (lane & 7);

    // Q fragments direct to registers (loop-invariant). A-layout: lane m=l15, k=quad*8+j.
    short8 qf[2][2];
    #pragma unroll
    for (int mi = 0; mi < 2; ++mi)
        #pragma unroll
        for (int ks = 0; ks < 2; ++ks)
            qf[mi][ks] = *(const short8*)(qp + (size_t)(b * SQ + s0 + wm + mi * 16 + l15) * DM
                                             + h * DKH + ks * 32 + quad * 8);

    f32x4 oacc[2][4];
    #pragma unroll
    for (int a = 0; a < 2; ++a)
        #pragma unroll
        for (int d = 0; d < 4; ++d)
            #pragma unroll
            for (int r = 0; r < 4; ++r) oacc[a][d][r] = 0.0f;
    float lsum[2][4] = {{0.f, 0.f, 0.f, 0.f}, {0.f, 0.f, 0.f, 0.f}};

    for (int j0 = 0; j0 < LCC; j0 += 64) {
        #pragma unroll
        for (int i = 0; i < 2; ++i) {
            int is = wave * 2 + i;
            int row = is * 8 + srow;
            int c = sc8 ^ (row & 7);
            int j = j0 + row; if (j > LCC - 1) j = LCC - 1;
            gl_lds16(kp + (size_t)(b * LCC + j) * DM + h * DKH + c * 8, Ks + is * 512 + lane * 8);
            gl_lds16(vt + (size_t)(bh * DKH + row) * LCP + j0 + c * 8,  Vts + is * 512 + lane * 8);
        }
        __syncthreads();

        // S = Q K^T (Q pre-scaled by 1/8)
        f32x4 sc[2][4];
        #pragma unroll
        for (int a = 0; a < 2; ++a)
            #pragma unroll
            for (int n = 0; n < 4; ++n)
                #pragma unroll
                for (int r = 0; r < 4; ++r) sc[a][n][r] = 0.0f;
        #pragma unroll
        for (int ks = 0; ks < 2; ++ks) {
            short8 bk[4];
            #pragma unroll
            for (int nj = 0; nj < 4; ++nj) {
                int n = nj * 16 + l15;
                int c = (ks * 4 + quad) ^ (n & 7);
                bk[nj] = *(const short8*)(Ks + n * 64 + c * 8);
            }
            #pragma unroll
            for (int mi = 0; mi < 2; ++mi)
                #pragma unroll
                for (int nj = 0; nj < 4; ++nj)
                    sc[mi][nj] = __builtin_amdgcn_mfma_f32_16x16x32_bf16(qf[mi][ks], bk[nj], sc[mi][nj], 0, 0, 0);
        }
        if (j0 + 64 > LCC) {
            #pragma unroll
            for (int nj = 0; nj < 4; ++nj) {
                if (j0 + nj * 16 + l15 >= LCC) {
                    #pragma unroll
                    for (int mi = 0; mi < 2; ++mi)
                        #pragma unroll
                        for (int r = 0; r < 4; ++r) sc[mi][nj][r] = -1e30f;
                }
            }
        }
        // p = exp(s); store into XOR-swizzled Ps; accumulate row sums (fp32)
        #pragma unroll
        for (int mi = 0; mi < 2; ++mi) {
            int pmb = wm + mi * 16 + quad * 4;
            #pragma unroll
            for (int nj = 0; nj < 4; ++nj) {
                int cw_ = nj * 2 + (l15 >> 3);   // global chunk of col
                int cl  = l15 & 7;
                #pragma unroll
                for (int r = 0; r < 4; ++r) {
                    float p = __expf(sc[mi][nj][r]);
                    lsum[mi][r] += p;
                    int row = pmb + r;
                    Ps[row * 64 + (cw_ ^ (row & 7)) * 8 + cl] = f2bf(p);
                }
            }
        }
        // PV (same-wave DS ordering: each wave reads only rows it wrote)
        #pragma unroll
        for (int ks = 0; ks < 2; ++ks) {
            short8 ap[2], bv[4];
            #pragma unroll
            for (int mi = 0; mi < 2; ++mi) {
                int m = wm + mi * 16 + l15;
                int c = (ks * 4 + quad) ^ (m & 7);
                ap[mi] = *(const short8*)(Ps + m * 64 + c * 8);
            }
            #pragma unroll
            for (int dj = 0; dj < 4; ++dj) {
                int d = dj * 16 + l15;
                int c = (ks * 4 + quad) ^ (d & 7);
                bv[dj] = *(const short8*)(Vts + d * 64 + c * 8);
            }
            #pragma unroll
            for (int mi = 0; mi < 2; ++mi)
                #pragma unroll
                for (int dj = 0; dj < 4; ++dj)
                    oacc[mi][dj] = __builtin_amdgcn_mfma_f32_16x16x32_bf16(ap[mi], bv[dj], oacc[mi][dj], 0, 0, 0);
        }
        __syncthreads();
    }
    #pragma unroll
    for (int mi = 0; mi < 2; ++mi) {
        #pragma unroll
        for (int r = 0; r < 4; ++r) {
            float v = lsum[mi][r];
            v += __shfl_xor(v, 1, 64); v += __shfl_xor(v, 2, 64);
            v += __shfl_xor(v, 4, 64); v += __shfl_xor(v, 8, 64);
            float inv = 1.0f / v;
            int s = s0 + wm + mi * 16 + quad * 4 + r;
            #pragma unroll
            for (int dj = 0; dj < 4; ++dj)
                xo[(size_t)(b * SQ + s) * DM + h * DKH + dj * 16 + l15] = f2bf(oacc[mi][dj][r] * inv);
        }
    }
}

extern "C" void kernel_launch(void* const* d_in, const int* in_sizes, int n_in,
                              void* d_out, int out_size, void* d_ws, size_t ws_size,
                              hipStream_t stream)
{
    const float* query  = (const float*)d_in[0];
    const float* key    = (const float*)d_in[1];
    const float* value  = (const float*)d_in[2];
    const float* Wq     = (const float*)d_in[3];
    const float* bq     = (const float*)d_in[4];
    const float* Wk     = (const float*)d_in[5];
    const float* bk     = (const float*)d_in[6];
    const float* Wv     = (const float*)d_in[7];
    const float* bv     = (const float*)d_in[8];
    const float* Wo     = (const float*)d_in[9];
    const float* bo     = (const float*)d_in[10];
    const float* conv_w = (const float*)d_in[11];
    const float* conv_b = (const float*)d_in[12];
    float* out = (float*)d_out;

    u16* p = (u16*)d_ws;
    auto alloc = [&](size_t n) { u16* r = p; p += (n + 127) & ~(size_t)127; return r; };
    u16* qbf  = alloc((size_t)BB * SQ * DM);
    u16* kpad = alloc((size_t)BB * SPAD * DM);
    u16* vpad = alloc((size_t)BB * SPAD * DM);
    u16* wqb  = alloc((size_t)DM * DM);
    u16* wkb  = alloc((size_t)DM * DM);
    u16* wvb  = alloc((size_t)DM * DM);
    u16* wob  = alloc((size_t)DM * DM);
    u16* wc2T = alloc((size_t)DM * DM * 3);      // [3072][1024]
    u16* Wkc  = alloc((size_t)DM * DM * 3);      // [1024][3072] composed
    u16* Wvc  = alloc((size_t)DM * DM * 3);
    u16* kpj  = alloc((size_t)BB * LCC * DM);
    u16* vpj  = alloc((size_t)BB * LCC * DM);
    u16* qprj = alloc((size_t)BB * SQ * DM);
    u16* vtb  = alloc((size_t)BB * NH * DKH * LCP);
    u16* xo   = alloc((size_t)BB * SQ * DM);
    float* biask = (float*)alloc(2 * DM);
    float* biasv = (float*)alloc(2 * DM);

    const int NC = BB * LCC;    // 5464
    const int NS = BB * SQ;     // 16384

    // casts & weight prep
    cast4_k<<<dim3(NS * DM / 4 / 256), 256, 0, stream>>>(query, qbf, NS * DM / 4, 1.0f);
    cast_pad_k<<<dim3((BB * SPAD * DM / 4 + 255) / 256), 256, 0, stream>>>(key, kpad);
    cast_pad_k<<<dim3((BB * SPAD * DM / 4 + 255) / 256), 256, 0, stream>>>(value, vpad);
    cast4_k<<<dim3(DM * DM / 4 / 256), 256, 0, stream>>>(Wq, wqb, DM * DM / 4, 0.125f);  // fold 1/sqrt(DK)
    cast4_k<<<dim3(DM * DM / 4 / 256), 256, 0, stream>>>(Wk, wkb, DM * DM / 4, 1.0f);
    cast4_k<<<dim3(DM * DM / 4 / 256), 256, 0, stream>>>(Wv, wvb, DM * DM / 4, 1.0f);
    cast4_k<<<dim3(DM * DM / 4 / 256), 256, 0, stream>>>(Wo, wob, DM * DM / 4, 1.0f);
    wc2t_k<<<dim3(16, 16, 3), 256, 0, stream>>>(conv_w, wc2T);
    bias_comp_k<<<dim3(256), 256, 0, stream>>>(Wk, conv_b, bk, biask);
    bias_comp_k<<<dim3(256), 256, 0, stream>>>(Wv, conv_b, bv, biasv);

    // weight compose: Wkc[o][k3] = sum_c Wk[o][c]*wc2T[k3][c]   (N=1024, K=1024, ldc=3072)
    gemm_mfma_k<<<dim3(24, 8, 2), 256, 0, stream>>>(
        wkb, wvb, wc2T, wc2T, nullptr, nullptr, Wkc, Wvc, DM, DM, 3 * DM, 0, 0.0f);

    // fused conv+proj: kpj/vpj = kpad/vpad (flat im2col view) · Wkc/Wvc^T + bias  (K=3072)
    gemm_mfma_k<<<dim3(8, 43, 2), 256, 0, stream>>>(
        kpad, vpad, Wkc, Wvc, biask, biasv, kpj, vpj, NC, 3 * DM, DM, 0, 1.0f);

    // q projection (1/8 folded)
    gemm_mfma_k<<<dim3(8, 128, 1), 256, 0, stream>>>(
        qbf, qbf, wqb, wqb, bq, bq, qprj, qprj, NS, DM, DM, 0, 0.125f);

    transpose_v_k<<<dim3(22, BB * NH), 256, 0, stream>>>(vpj, vtb);

    attn_mfma_k<<<dim3(SQ / 128, BB * NH), 256, 0, stream>>>(qprj, kpj, vtb, xo);

    // output projection -> fp32 d_out
    gemm_mfma_k<<<dim3(8, 128, 1), 256, 0, stream>>>(
        xo, xo, wob, wob, bo, bo, out, out, NS, DM, DM, 1, 1.0f);
}